// Round 1
// baseline (206.556 us; speedup 1.0000x reference)
//
#include <hip/hip_runtime.h>
#include <hip/hip_bf16.h>
#include <math.h>

// Problem constants: B=1, T=256, D=512, M=64, H=8, HD=64, IN=256, HID=256
#define T_ 256
#define D_ 512
#define M_ 64
#define H_ 8
#define HD_ 64
#define HID_ 256

// ---------------------------------------------------------------------------
// Generic tiled fp32 GEMM: C[z] = act( A[z] @ B[z] + ADD + bias )
// 32x32 tile, 256 threads, 2x2 micro-tile. All dims multiples of 32.
// ---------------------------------------------------------------------------
__global__ __launch_bounds__(256) void gemm_kernel(
    const float* __restrict__ A, int lda, int sA,
    const float* __restrict__ B, int ldb, int sB,
    float* __restrict__ C, int ldc, int sC,
    const float* __restrict__ ADD, int ldadd,
    const float* __restrict__ bias,
    int M, int N, int K, int act)
{
    const int z = blockIdx.z;
    A += (long)z * sA;
    B += (long)z * sB;
    C += (long)z * sC;

    __shared__ float As[32][33];
    __shared__ float Bs[32][33];

    const int tid = threadIdx.x;
    const int tx = tid & 15;       // 0..15 (output col group)
    const int ty = tid >> 4;       // 0..15 (output row group)
    const int row0 = blockIdx.y * 32;
    const int col0 = blockIdx.x * 32;

    float acc00 = 0.f, acc01 = 0.f, acc10 = 0.f, acc11 = 0.f;

    for (int k0 = 0; k0 < K; k0 += 32) {
        // load 32x32 A and B tiles (1024 elems each, 4 per thread)
        #pragma unroll
        for (int l = 0; l < 4; ++l) {
            int idx = tid + l * 256;
            int r = idx >> 5, c = idx & 31;
            As[r][c] = A[(long)(row0 + r) * lda + (k0 + c)];
            Bs[r][c] = B[(long)(k0 + r) * ldb + (col0 + c)];
        }
        __syncthreads();
        #pragma unroll
        for (int kk = 0; kk < 32; ++kk) {
            float a0 = As[ty * 2 + 0][kk];
            float a1 = As[ty * 2 + 1][kk];
            float b0 = Bs[kk][tx * 2 + 0];
            float b1 = Bs[kk][tx * 2 + 1];
            acc00 += a0 * b0; acc01 += a0 * b1;
            acc10 += a1 * b0; acc11 += a1 * b1;
        }
        __syncthreads();
    }

    float accs[2][2] = {{acc00, acc01}, {acc10, acc11}};
    #pragma unroll
    for (int ii = 0; ii < 2; ++ii) {
        #pragma unroll
        for (int jj = 0; jj < 2; ++jj) {
            int r = row0 + ty * 2 + ii;
            int c = col0 + tx * 2 + jj;
            float v = accs[ii][jj];
            if (ADD)  v += ADD[(long)r * ldadd + c];
            if (bias) v += bias[c];
            if (act)  v = v * __builtin_amdgcn_rcpf(1.f + __expf(-v)); // silu
            C[(long)r * ldc + c] = v;
        }
    }
}

// ---------------------------------------------------------------------------
// Pairwise kernel: linking[h,i,j] = tanh(0.5*(b2d + sum_f silu(ai+aj)*w2d))
// Block: (i-tile of 16) x (j-half of 128). 256 threads -> 16x16 pair tile,
// loops 8 j-chunks of 16. Also emits per-block partial sums for writhe /
// linking_mean (deterministic two-stage reduction).
// ---------------------------------------------------------------------------
__global__ __launch_bounds__(256) void pairwise_kernel(
    const float* __restrict__ a_i, const float* __restrict__ a_j,
    const float* __restrict__ W2, const float* __restrict__ b2,
    float* __restrict__ linking, float* __restrict__ partials)
{
    const int h  = blockIdx.z;   // 0..7
    const int it = blockIdx.x;   // 0..15  (i tile)
    const int jh = blockIdx.y;   // 0..1   (j half)
    const int tid = threadIdx.x;

    __shared__ __align__(16) float ai_s[16][260];
    __shared__ __align__(16) float aj_s[16][260];
    __shared__ __align__(16) float w2d_s[256];
    __shared__ float red[256];

    // w2diff
    w2d_s[tid] = W2[tid * 2 + 0] - W2[tid * 2 + 1];
    const float b2d = b2[0] - b2[1];

    // load a_i tile (16 rows x 256)
    const float* aib = a_i + ((long)h * T_ + it * 16) * HID_;
    #pragma unroll
    for (int l = 0; l < 4; ++l) {
        int idx = tid + l * 256;       // float4 index 0..1023
        int r = idx >> 6, c4 = idx & 63;
        float4 v = ((const float4*)(aib + (long)r * HID_))[c4];
        *(float4*)&ai_s[r][c4 * 4] = v;
    }

    const int i_loc = tid >> 4;
    const int j_loc = tid & 15;
    const int i_glob = it * 16 + i_loc;

    float sum_l = 0.f, sum_abs = 0.f;

    for (int jt = 0; jt < 8; ++jt) {
        const int j0 = jh * 128 + jt * 16;
        __syncthreads();   // protect aj_s reuse (also covers initial loads)
        const float* ajb = a_j + ((long)h * T_ + j0) * HID_;
        #pragma unroll
        for (int l = 0; l < 4; ++l) {
            int idx = tid + l * 256;
            int r = idx >> 6, c4 = idx & 63;
            float4 v = ((const float4*)(ajb + (long)r * HID_))[c4];
            *(float4*)&aj_s[r][c4 * 4] = v;
        }
        __syncthreads();

        float s = b2d;
        #pragma unroll 8
        for (int f4 = 0; f4 < 64; ++f4) {
            float4 av = *(const float4*)&ai_s[i_loc][f4 * 4];
            float4 bv = *(const float4*)&aj_s[j_loc][f4 * 4];
            float4 wv = *(const float4*)&w2d_s[f4 * 4];
            float t, e;
            t = av.x + bv.x; e = __expf(-t); s += wv.x * t * __builtin_amdgcn_rcpf(1.f + e);
            t = av.y + bv.y; e = __expf(-t); s += wv.y * t * __builtin_amdgcn_rcpf(1.f + e);
            t = av.z + bv.z; e = __expf(-t); s += wv.z * t * __builtin_amdgcn_rcpf(1.f + e);
            t = av.w + bv.w; e = __expf(-t); s += wv.w * t * __builtin_amdgcn_rcpf(1.f + e);
        }
        float lk = tanhf(0.5f * s);
        linking[((long)h * T_ + i_glob) * T_ + (j0 + j_loc)] = lk;
        sum_l += lk;
        sum_abs += fabsf(lk);
    }

    // block reduction of (sum_l, sum_abs)
    __syncthreads();
    red[tid] = sum_l;
    __syncthreads();
    for (int off = 128; off > 0; off >>= 1) {
        if (tid < off) red[tid] += red[tid + off];
        __syncthreads();
    }
    float tot_l = red[0];
    __syncthreads();
    red[tid] = sum_abs;
    __syncthreads();
    for (int off = 128; off > 0; off >>= 1) {
        if (tid < off) red[tid] += red[tid + off];
        __syncthreads();
    }
    if (tid == 0) {
        int slot = h * 32 + jh * 16 + it;
        partials[slot * 2 + 0] = tot_l;
        partials[slot * 2 + 1] = red[0];
    }
}

// ---------------------------------------------------------------------------
// Final reduce: writhe[8] and linking_mean from 256 block partials.
// ---------------------------------------------------------------------------
__global__ __launch_bounds__(64) void reduce_kernel(
    const float* __restrict__ partials, float* __restrict__ out_tail)
{
    const int lane = threadIdx.x;
    float a = 0.f;
    for (int e = lane; e < 256; e += 64) a += partials[e * 2 + 1];
    for (int off = 32; off > 0; off >>= 1) a += __shfl_xor(a, off);
    if (lane < 8) {
        float w = 0.f;
        for (int b = 0; b < 32; ++b) w += partials[(lane * 32 + b) * 2 + 0];
        out_tail[lane] = w;
    }
    if (lane == 0) out_tail[8] = a / (float)(H_ * T_ * T_);
}

// ---------------------------------------------------------------------------
// Causal softmax + PV. One 64-lane wave per (head, row).
// ---------------------------------------------------------------------------
__global__ __launch_bounds__(64) void attn_kernel(
    const float* __restrict__ linking, const float* __restrict__ yv,
    float* __restrict__ o)
{
    const int i = blockIdx.x;
    const int h = blockIdx.y;
    const int lane = threadIdx.x;

    const float* lrow = linking + ((long)h * T_ + i) * T_;
    __shared__ float p[T_];

    float sv[4];
    float m = -1e30f;
    #pragma unroll
    for (int r = 0; r < 4; ++r) {
        int j = lane + r * 64;
        float s = (j <= i) ? lrow[j] * 0.125f : -1e30f;
        sv[r] = s;
        m = fmaxf(m, s);
    }
    for (int off = 32; off > 0; off >>= 1) m = fmaxf(m, __shfl_xor(m, off));

    float sum = 0.f;
    #pragma unroll
    for (int r = 0; r < 4; ++r) {
        int j = lane + r * 64;
        float e = (j <= i) ? __expf(sv[r] - m) : 0.f;
        p[j] = e;
        sum += e;
    }
    for (int off = 32; off > 0; off >>= 1) sum += __shfl_xor(sum, off);
    __syncthreads();

    const float inv = __builtin_amdgcn_rcpf(sum);
    const int d = lane;
    const float* vb = yv + h * HD_ + d;
    float acc = 0.f;
    for (int j = 0; j <= i; ++j) acc += p[j] * vb[(long)j * D_];
    o[(long)i * D_ + h * HD_ + d] = acc * inv;
}

// ---------------------------------------------------------------------------
extern "C" void kernel_launch(void* const* d_in, const int* in_sizes, int n_in,
                              void* d_out, int out_size, void* d_ws, size_t ws_size,
                              hipStream_t stream)
{
    const float* x      = (const float*)d_in[0];
    const float* coords = (const float*)d_in[1];
    const float* Wq     = (const float*)d_in[2];
    const float* Wk     = (const float*)d_in[3];
    const float* Wv     = (const float*)d_in[4];
    const float* Wo     = (const float*)d_in[5];
    const float* W1     = (const float*)d_in[6];
    const float* b1     = (const float*)d_in[7];
    const float* W2     = (const float*)d_in[8];
    const float* b2     = (const float*)d_in[9];
    const float* W3     = (const float*)d_in[10];
    const float* b3     = (const float*)d_in[11];
    const float* W4     = (const float*)d_in[12];
    const float* b4     = (const float*)d_in[13];
    float* out = (float*)d_out;

    float* ws = (float*)d_ws;
    float* yq   = ws;                  // 256*512
    float* yk   = ws + 131072;
    float* yv   = ws + 262144;
    float* ci   = ws + 393216;         // 256*256
    float* cj   = ws + 458752;
    float* ai   = ws + 524288;         // 8*256*256
    float* aj   = ws + 1048576;
    float* lk   = ws + 1572864;        // 8*256*256
    float* o    = ws + 2097152;        // 256*512
    float* g1   = ws + 2228224;
    float* g2   = ws + 2359296;
    float* parts= ws + 2490368;        // 256*2

    dim3 blk(256);

    // 1) q,k,v projections: y = x @ W   (256x512x512)
    gemm_kernel<<<dim3(16, 8, 1), blk, 0, stream>>>(x, D_, 0, Wq, D_, 0, yq, D_, 0,
                                                    nullptr, 0, nullptr, T_, D_, D_, 0);
    gemm_kernel<<<dim3(16, 8, 1), blk, 0, stream>>>(x, D_, 0, Wk, D_, 0, yk, D_, 0,
                                                    nullptr, 0, nullptr, T_, D_, D_, 0);
    gemm_kernel<<<dim3(16, 8, 1), blk, 0, stream>>>(x, D_, 0, Wv, D_, 0, yv, D_, 0,
                                                    nullptr, 0, nullptr, T_, D_, D_, 0);

    // 2) coords projections: ci = coords@W1ci ; cj = coords@W1cj + b1
    gemm_kernel<<<dim3(8, 8, 1), blk, 0, stream>>>(coords, M_, 0, W1 + 128 * HID_, HID_, 0,
                                                   ci, HID_, 0, nullptr, 0, nullptr,
                                                   T_, HID_, M_, 0);
    gemm_kernel<<<dim3(8, 8, 1), blk, 0, stream>>>(coords, M_, 0, W1 + 192 * HID_, HID_, 0,
                                                   cj, HID_, 0, nullptr, 0, b1,
                                                   T_, HID_, M_, 0);

    // 3) a_i[h] = yq[:, h*64:(h+1)*64] @ W1q + ci ;  a_j[h] = ... @ W1k + cj
    gemm_kernel<<<dim3(8, 8, 8), blk, 0, stream>>>(yq, D_, HD_, W1, HID_, 0,
                                                   ai, HID_, T_ * HID_, ci, HID_, nullptr,
                                                   T_, HID_, HD_, 0);
    gemm_kernel<<<dim3(8, 8, 8), blk, 0, stream>>>(yk, D_, HD_, W1 + 64 * HID_, HID_, 0,
                                                   aj, HID_, T_ * HID_, cj, HID_, nullptr,
                                                   T_, HID_, HD_, 0);

    // 4) pairwise silu-MLP -> linking + partial sums
    pairwise_kernel<<<dim3(16, 2, 8), blk, 0, stream>>>(ai, aj, W2, b2, lk, parts);

    // 5) writhe + linking_mean
    reduce_kernel<<<dim3(1), dim3(64), 0, stream>>>(parts, out + 131072);

    // 6) causal softmax + PV
    attn_kernel<<<dim3(T_, H_), dim3(64), 0, stream>>>(lk, yv, o);

    // 7) epilogue: out = (silu(o@W3+b3) @ W4 + b4) @ Wo
    gemm_kernel<<<dim3(16, 8, 1), blk, 0, stream>>>(o, D_, 0, W3, D_, 0, g1, D_, 0,
                                                    nullptr, 0, b3, T_, D_, D_, 1);
    gemm_kernel<<<dim3(16, 8, 1), blk, 0, stream>>>(g1, D_, 0, W4, D_, 0, g2, D_, 0,
                                                    nullptr, 0, b4, T_, D_, D_, 0);
    gemm_kernel<<<dim3(16, 8, 1), blk, 0, stream>>>(g2, D_, 0, Wo, D_, 0, out, D_, 0,
                                                    nullptr, 0, nullptr, T_, D_, D_, 0);
}

// Round 2
// 147.765 us; speedup vs baseline: 1.3979x; 1.3979x over previous
//
#include <hip/hip_runtime.h>
#include <hip/hip_bf16.h>
#include <math.h>

// Problem constants: B=1, T=256, D=512, M=64, H=8, HD=64, IN=256, HID=256
#define T_ 256
#define D_ 512
#define M_ 64
#define H_ 8
#define HD_ 64
#define HID_ 256

// ---------------------------------------------------------------------------
// Generic tiled fp32 GEMM: C = act( A @ B + bias )  (used for epilogue chain)
// 32x32 tile, 256 threads, 2x2 micro-tile.
// ---------------------------------------------------------------------------
__global__ __launch_bounds__(256) void gemm_kernel(
    const float* __restrict__ A, int lda,
    const float* __restrict__ B, int ldb,
    float* __restrict__ C, int ldc,
    const float* __restrict__ bias,
    int M, int N, int K, int act)
{
    __shared__ float As[32][33];
    __shared__ float Bs[32][33];

    const int tid = threadIdx.x;
    const int tx = tid & 15;
    const int ty = tid >> 4;
    const int row0 = blockIdx.y * 32;
    const int col0 = blockIdx.x * 32;

    float acc00 = 0.f, acc01 = 0.f, acc10 = 0.f, acc11 = 0.f;

    for (int k0 = 0; k0 < K; k0 += 32) {
        #pragma unroll
        for (int l = 0; l < 4; ++l) {
            int idx = tid + l * 256;
            int r = idx >> 5, c = idx & 31;
            As[r][c] = A[(long)(row0 + r) * lda + (k0 + c)];
            Bs[r][c] = B[(long)(k0 + r) * ldb + (col0 + c)];
        }
        __syncthreads();
        #pragma unroll
        for (int kk = 0; kk < 32; ++kk) {
            float a0 = As[ty * 2 + 0][kk];
            float a1 = As[ty * 2 + 1][kk];
            float b0 = Bs[kk][tx * 2 + 0];
            float b1 = Bs[kk][tx * 2 + 1];
            acc00 += a0 * b0; acc01 += a0 * b1;
            acc10 += a1 * b0; acc11 += a1 * b1;
        }
        __syncthreads();
    }

    float accs[2][2] = {{acc00, acc01}, {acc10, acc11}};
    #pragma unroll
    for (int ii = 0; ii < 2; ++ii) {
        #pragma unroll
        for (int jj = 0; jj < 2; ++jj) {
            int r = row0 + ty * 2 + ii;
            int c = col0 + tx * 2 + jj;
            float v = accs[ii][jj];
            if (bias) v += bias[c];
            if (act)  v = v * __builtin_amdgcn_rcpf(1.f + __expf(-v)); // silu
            C[(long)r * ldc + c] = v;
        }
    }
}

// ---------------------------------------------------------------------------
// Fused QKV projection: y[z] = x @ W[z], z in {q,k,v}. Grid (16, 8, 3).
// ---------------------------------------------------------------------------
__global__ __launch_bounds__(256) void qkv_kernel(
    const float* __restrict__ x,
    const float* __restrict__ Wq, const float* __restrict__ Wk,
    const float* __restrict__ Wv, float* __restrict__ y)
{
    const int z = blockIdx.z;
    const float* W = (z == 0) ? Wq : (z == 1) ? Wk : Wv;
    float* C = y + (long)z * (T_ * D_);

    __shared__ float As[32][33];
    __shared__ float Bs[32][33];

    const int tid = threadIdx.x;
    const int tx = tid & 15;
    const int ty = tid >> 4;
    const int row0 = blockIdx.y * 32;
    const int col0 = blockIdx.x * 32;

    float acc00 = 0.f, acc01 = 0.f, acc10 = 0.f, acc11 = 0.f;

    for (int k0 = 0; k0 < D_; k0 += 32) {
        #pragma unroll
        for (int l = 0; l < 4; ++l) {
            int idx = tid + l * 256;
            int r = idx >> 5, c = idx & 31;
            As[r][c] = x[(long)(row0 + r) * D_ + (k0 + c)];
            Bs[r][c] = W[(long)(k0 + r) * D_ + (col0 + c)];
        }
        __syncthreads();
        #pragma unroll
        for (int kk = 0; kk < 32; ++kk) {
            float a0 = As[ty * 2 + 0][kk];
            float a1 = As[ty * 2 + 1][kk];
            float b0 = Bs[kk][tx * 2 + 0];
            float b1 = Bs[kk][tx * 2 + 1];
            acc00 += a0 * b0; acc01 += a0 * b1;
            acc10 += a1 * b0; acc11 += a1 * b1;
        }
        __syncthreads();
    }
    C[(long)(row0 + ty * 2 + 0) * D_ + col0 + tx * 2 + 0] = acc00;
    C[(long)(row0 + ty * 2 + 0) * D_ + col0 + tx * 2 + 1] = acc01;
    C[(long)(row0 + ty * 2 + 1) * D_ + col0 + tx * 2 + 0] = acc10;
    C[(long)(row0 + ty * 2 + 1) * D_ + col0 + tx * 2 + 1] = acc11;
}

// ---------------------------------------------------------------------------
// Fused coords projection: cc[z] = coords @ W1c[z] (+ b1 for z==1).
// Grid (8, 8, 2). K = 64.
// ---------------------------------------------------------------------------
__global__ __launch_bounds__(256) void coords_kernel(
    const float* __restrict__ coords, const float* __restrict__ W1,
    const float* __restrict__ b1, float* __restrict__ cc)
{
    const int z = blockIdx.z;
    const float* B = W1 + (long)(128 + 64 * z) * HID_;
    float* C = cc + (long)z * (T_ * HID_);

    __shared__ float As[32][33];
    __shared__ float Bs[32][33];

    const int tid = threadIdx.x;
    const int tx = tid & 15;
    const int ty = tid >> 4;
    const int row0 = blockIdx.y * 32;
    const int col0 = blockIdx.x * 32;

    float acc00 = 0.f, acc01 = 0.f, acc10 = 0.f, acc11 = 0.f;

    for (int k0 = 0; k0 < M_; k0 += 32) {
        #pragma unroll
        for (int l = 0; l < 4; ++l) {
            int idx = tid + l * 256;
            int r = idx >> 5, c = idx & 31;
            As[r][c] = coords[(long)(row0 + r) * M_ + (k0 + c)];
            Bs[r][c] = B[(long)(k0 + r) * HID_ + (col0 + c)];
        }
        __syncthreads();
        #pragma unroll
        for (int kk = 0; kk < 32; ++kk) {
            float a0 = As[ty * 2 + 0][kk];
            float a1 = As[ty * 2 + 1][kk];
            float b0 = Bs[kk][tx * 2 + 0];
            float b1 = Bs[kk][tx * 2 + 1];
            acc00 += a0 * b0; acc01 += a0 * b1;
            acc10 += a1 * b0; acc11 += a1 * b1;
        }
        __syncthreads();
    }
    float bb0 = (z == 1) ? b1[col0 + tx * 2 + 0] : 0.f;
    float bb1 = (z == 1) ? b1[col0 + tx * 2 + 1] : 0.f;
    C[(long)(row0 + ty * 2 + 0) * HID_ + col0 + tx * 2 + 0] = acc00 + bb0;
    C[(long)(row0 + ty * 2 + 0) * HID_ + col0 + tx * 2 + 1] = acc01 + bb1;
    C[(long)(row0 + ty * 2 + 1) * HID_ + col0 + tx * 2 + 0] = acc10 + bb0;
    C[(long)(row0 + ty * 2 + 1) * HID_ + col0 + tx * 2 + 1] = acc11 + bb1;
}

// ---------------------------------------------------------------------------
// Fused a_i / a_j: for z = sel*8 + h:
//   abuf[z] = y[sel][:, h*64:(h+1)*64] @ W1[sel*64:(sel+1)*64] + cc[sel]
// Grid (8, 8, 16). K = 64.
// ---------------------------------------------------------------------------
__global__ __launch_bounds__(256) void aiaj_kernel(
    const float* __restrict__ y, const float* __restrict__ W1,
    const float* __restrict__ cc, float* __restrict__ abuf)
{
    const int z = blockIdx.z;
    const int sel = z >> 3;      // 0 = a_i (from q), 1 = a_j (from k)
    const int h = z & 7;
    const float* A = y + (long)sel * (T_ * D_) + h * HD_;
    const float* B = W1 + (long)sel * 64 * HID_;
    const float* ADD = cc + (long)sel * (T_ * HID_);
    float* C = abuf + (long)z * (T_ * HID_);

    __shared__ float As[32][33];
    __shared__ float Bs[32][33];

    const int tid = threadIdx.x;
    const int tx = tid & 15;
    const int ty = tid >> 4;
    const int row0 = blockIdx.y * 32;
    const int col0 = blockIdx.x * 32;

    float acc00 = 0.f, acc01 = 0.f, acc10 = 0.f, acc11 = 0.f;

    for (int k0 = 0; k0 < HD_; k0 += 32) {
        #pragma unroll
        for (int l = 0; l < 4; ++l) {
            int idx = tid + l * 256;
            int r = idx >> 5, c = idx & 31;
            As[r][c] = A[(long)(row0 + r) * D_ + (k0 + c)];
            Bs[r][c] = B[(long)(k0 + r) * HID_ + (col0 + c)];
        }
        __syncthreads();
        #pragma unroll
        for (int kk = 0; kk < 32; ++kk) {
            float a0 = As[ty * 2 + 0][kk];
            float a1 = As[ty * 2 + 1][kk];
            float b0 = Bs[kk][tx * 2 + 0];
            float b1 = Bs[kk][tx * 2 + 1];
            acc00 += a0 * b0; acc01 += a0 * b1;
            acc10 += a1 * b0; acc11 += a1 * b1;
        }
        __syncthreads();
    }
    {
        int r0 = row0 + ty * 2, c0 = col0 + tx * 2;
        C[(long)(r0 + 0) * HID_ + c0 + 0] = acc00 + ADD[(long)(r0 + 0) * HID_ + c0 + 0];
        C[(long)(r0 + 0) * HID_ + c0 + 1] = acc01 + ADD[(long)(r0 + 0) * HID_ + c0 + 1];
        C[(long)(r0 + 1) * HID_ + c0 + 0] = acc10 + ADD[(long)(r0 + 1) * HID_ + c0 + 0];
        C[(long)(r0 + 1) * HID_ + c0 + 1] = acc11 + ADD[(long)(r0 + 1) * HID_ + c0 + 1];
    }
}

// ---------------------------------------------------------------------------
// Pairwise kernel v2: 32x32 (i,j) tile per block, 2x2 per-thread micro-tile.
// linking[h,i,j] = tanh(0.5*(b2d + sum_f silu(ai+aj)*w2d))
// Grid (8 jt, 8 it, 8 h) = 512 blocks of 256 threads.
// ---------------------------------------------------------------------------
#define SILU_ACC(acc, w, aa, bb) \
    { float t_ = (aa) + (bb); \
      float sg_ = __builtin_amdgcn_rcpf(1.f + __expf(-t_)); \
      acc = fmaf((w) * t_, sg_, acc); }

__global__ __launch_bounds__(256) void pairwise_kernel(
    const float* __restrict__ a_i, const float* __restrict__ a_j,
    const float* __restrict__ W2, const float* __restrict__ b2,
    float* __restrict__ linking, float* __restrict__ partials)
{
    const int jt = blockIdx.x;
    const int it = blockIdx.y;
    const int h  = blockIdx.z;
    const int tid = threadIdx.x;

    __shared__ __align__(16) float ai_s[32][260];
    __shared__ __align__(16) float aj_s[32][260];
    __shared__ __align__(16) float w2d_s[256];
    __shared__ float red[256];

    w2d_s[tid] = W2[tid * 2 + 0] - W2[tid * 2 + 1];
    const float b2d = b2[0] - b2[1];

    const float* aib = a_i + ((long)h * T_ + it * 32) * HID_;
    const float* ajb = a_j + ((long)h * T_ + jt * 32) * HID_;
    #pragma unroll
    for (int l = 0; l < 8; ++l) {
        int idx = tid + l * 256;   // float4 index 0..2047
        int r = idx >> 6, c4 = idx & 63;
        *(float4*)&ai_s[r][c4 * 4] = *(const float4*)(aib + (long)r * HID_ + c4 * 4);
        *(float4*)&aj_s[r][c4 * 4] = *(const float4*)(ajb + (long)r * HID_ + c4 * 4);
    }
    __syncthreads();

    const int ty = tid >> 4;   // 0..15
    const int tx = tid & 15;   // 0..15
    const int i0 = ty, i1 = ty + 16;
    const int j0 = tx, j1 = tx + 16;

    float s00 = 0.f, s01 = 0.f, s10 = 0.f, s11 = 0.f;

    #pragma unroll 4
    for (int f4 = 0; f4 < 64; ++f4) {
        float4 a0 = *(const float4*)&ai_s[i0][f4 * 4];
        float4 a1 = *(const float4*)&ai_s[i1][f4 * 4];
        float4 c0 = *(const float4*)&aj_s[j0][f4 * 4];
        float4 c1 = *(const float4*)&aj_s[j1][f4 * 4];
        float4 w  = *(const float4*)&w2d_s[f4 * 4];
        SILU_ACC(s00, w.x, a0.x, c0.x); SILU_ACC(s01, w.x, a0.x, c1.x);
        SILU_ACC(s10, w.x, a1.x, c0.x); SILU_ACC(s11, w.x, a1.x, c1.x);
        SILU_ACC(s00, w.y, a0.y, c0.y); SILU_ACC(s01, w.y, a0.y, c1.y);
        SILU_ACC(s10, w.y, a1.y, c0.y); SILU_ACC(s11, w.y, a1.y, c1.y);
        SILU_ACC(s00, w.z, a0.z, c0.z); SILU_ACC(s01, w.z, a0.z, c1.z);
        SILU_ACC(s10, w.z, a1.z, c0.z); SILU_ACC(s11, w.z, a1.z, c1.z);
        SILU_ACC(s00, w.w, a0.w, c0.w); SILU_ACC(s01, w.w, a0.w, c1.w);
        SILU_ACC(s10, w.w, a1.w, c0.w); SILU_ACC(s11, w.w, a1.w, c1.w);
    }

    float l00 = tanhf(0.5f * (s00 + b2d));
    float l01 = tanhf(0.5f * (s01 + b2d));
    float l10 = tanhf(0.5f * (s10 + b2d));
    float l11 = tanhf(0.5f * (s11 + b2d));

    float* lb = linking + ((long)h * T_) * T_;
    const int gi0 = it * 32 + i0, gi1 = it * 32 + i1;
    const int gj0 = jt * 32 + j0, gj1 = jt * 32 + j1;
    lb[(long)gi0 * T_ + gj0] = l00;
    lb[(long)gi0 * T_ + gj1] = l01;
    lb[(long)gi1 * T_ + gj0] = l10;
    lb[(long)gi1 * T_ + gj1] = l11;

    float sum_l = l00 + l01 + l10 + l11;
    float sum_abs = fabsf(l00) + fabsf(l01) + fabsf(l10) + fabsf(l11);

    __syncthreads();
    red[tid] = sum_l;
    __syncthreads();
    for (int off = 128; off > 0; off >>= 1) {
        if (tid < off) red[tid] += red[tid + off];
        __syncthreads();
    }
    float tot_l = red[0];
    __syncthreads();
    red[tid] = sum_abs;
    __syncthreads();
    for (int off = 128; off > 0; off >>= 1) {
        if (tid < off) red[tid] += red[tid + off];
        __syncthreads();
    }
    if (tid == 0) {
        int slot = h * 64 + it * 8 + jt;
        partials[slot * 2 + 0] = tot_l;
        partials[slot * 2 + 1] = red[0];
    }
}

// ---------------------------------------------------------------------------
// Final reduce: writhe[8] and linking_mean from 512 block partials.
// ---------------------------------------------------------------------------
__global__ __launch_bounds__(64) void reduce_kernel(
    const float* __restrict__ partials, float* __restrict__ out_tail)
{
    const int lane = threadIdx.x;
    float a = 0.f;
    for (int e = lane; e < 512; e += 64) a += partials[e * 2 + 1];
    for (int off = 32; off > 0; off >>= 1) a += __shfl_xor(a, off);
    if (lane < 8) {
        float w = 0.f;
        for (int b = 0; b < 64; ++b) w += partials[(lane * 64 + b) * 2 + 0];
        out_tail[lane] = w;
    }
    if (lane == 0) out_tail[8] = a / (float)(H_ * T_ * T_);
}

// ---------------------------------------------------------------------------
// Causal softmax + PV. One 64-lane wave per (head, row).
// ---------------------------------------------------------------------------
__global__ __launch_bounds__(64) void attn_kernel(
    const float* __restrict__ linking, const float* __restrict__ yv,
    float* __restrict__ o)
{
    const int i = blockIdx.x;
    const int h = blockIdx.y;
    const int lane = threadIdx.x;

    const float* lrow = linking + ((long)h * T_ + i) * T_;
    __shared__ float p[T_];

    float sv[4];
    float m = -1e30f;
    #pragma unroll
    for (int r = 0; r < 4; ++r) {
        int j = lane + r * 64;
        float s = (j <= i) ? lrow[j] * 0.125f : -1e30f;
        sv[r] = s;
        m = fmaxf(m, s);
    }
    for (int off = 32; off > 0; off >>= 1) m = fmaxf(m, __shfl_xor(m, off));

    float sum = 0.f;
    #pragma unroll
    for (int r = 0; r < 4; ++r) {
        int j = lane + r * 64;
        float e = (j <= i) ? __expf(sv[r] - m) : 0.f;
        p[j] = e;
        sum += e;
    }
    for (int off = 32; off > 0; off >>= 1) sum += __shfl_xor(sum, off);
    __syncthreads();

    const float inv = __builtin_amdgcn_rcpf(sum);
    const int d = lane;
    const float* vb = yv + 2 * (T_ * D_) + h * HD_ + d;   // yv = y + 2*T*D
    float acc = 0.f;
    for (int j = 0; j <= i; ++j) acc += p[j] * vb[(long)j * D_];
    o[(long)i * D_ + h * HD_ + d] = acc * inv;
}

// ---------------------------------------------------------------------------
extern "C" void kernel_launch(void* const* d_in, const int* in_sizes, int n_in,
                              void* d_out, int out_size, void* d_ws, size_t ws_size,
                              hipStream_t stream)
{
    const float* x      = (const float*)d_in[0];
    const float* coords = (const float*)d_in[1];
    const float* Wq     = (const float*)d_in[2];
    const float* Wk     = (const float*)d_in[3];
    const float* Wv     = (const float*)d_in[4];
    const float* Wo     = (const float*)d_in[5];
    const float* W1     = (const float*)d_in[6];
    const float* b1     = (const float*)d_in[7];
    const float* W2     = (const float*)d_in[8];
    const float* b2     = (const float*)d_in[9];
    const float* W3     = (const float*)d_in[10];
    const float* b3     = (const float*)d_in[11];
    const float* W4     = (const float*)d_in[12];
    const float* b4     = (const float*)d_in[13];
    float* out = (float*)d_out;

    float* ws = (float*)d_ws;
    float* y    = ws;                   // yq|yk|yv : 3 * 256*512
    float* cc   = ws + 393216;          // ci|cj : 2 * 256*256
    float* abuf = ws + 524288;          // ai(8)|aj(8) : 16 * 256*256
    float* lkb  = ws + 1572864;         // 8*256*256
    float* o    = ws + 2097152;         // 256*512
    float* g1   = ws + 2228224;
    float* g2   = ws + 2359296;
    float* parts= ws + 2490368;         // 512*2

    dim3 blk(256);

    // 1) q,k,v projections (one dispatch)
    qkv_kernel<<<dim3(16, 8, 3), blk, 0, stream>>>(x, Wq, Wk, Wv, y);

    // 2) coords projections (one dispatch)
    coords_kernel<<<dim3(8, 8, 2), blk, 0, stream>>>(coords, W1, b1, cc);

    // 3) a_i / a_j (one dispatch, z = 16)
    aiaj_kernel<<<dim3(8, 8, 16), blk, 0, stream>>>(y, W1, cc, abuf);

    // 4) pairwise silu-MLP -> linking + partial sums
    pairwise_kernel<<<dim3(8, 8, 8), blk, 0, stream>>>(
        abuf, abuf + 8 * T_ * HID_, W2, b2, lkb, parts);

    // 5) writhe + linking_mean
    reduce_kernel<<<dim3(1), dim3(64), 0, stream>>>(parts, out + 131072);

    // 6) causal softmax + PV
    attn_kernel<<<dim3(T_, H_), dim3(64), 0, stream>>>(lkb, y, o);

    // 7) epilogue: out = (silu(o@W3+b3) @ W4 + b4) @ Wo
    gemm_kernel<<<dim3(16, 8, 1), blk, 0, stream>>>(o, D_, W3, D_, g1, D_, b3,
                                                    T_, D_, D_, 1);
    gemm_kernel<<<dim3(16, 8, 1), blk, 0, stream>>>(g1, D_, W4, D_, g2, D_, b4,
                                                    T_, D_, D_, 0);
    gemm_kernel<<<dim3(16, 8, 1), blk, 0, stream>>>(g2, D_, Wo, D_, out, D_, nullptr,
                                                    T_, D_, D_, 0);
}